// Round 6
// baseline (488.592 us; speedup 1.0000x reference)
//
#include <hip/hip_runtime.h>

// Bit-serial SAR ADC quantizer.
// Outputs concatenated in d_out: q [8192*1024] f32, Q [8192*1024*8] f32 (bit innermost), W [36] f32.
//
// R1: LDS-coalesced Q stores: 167.8 us vs R0 direct 158.7 -> LDS path is a NET
//     LOSS (L2 merges per-thread 128B-contiguous stores fine; LDS roundtrip +
//     barrier costs ~9-12 us).
// R2/R4: write traffic is ~2x ours: each replay drains the PREVIOUS replay's
//     ~288 MiB dirty output from LLC+L2 (structural, not fixable in-kernel).
//     nt builtins (allocate + LRU-deprioritize): 155.2 us.
// R5: asm `sc0 sc1 nt` write-around stores FAILED validation (stale lines
//     served to read-back). Cache-bypass is unsafe here; reverted.
// R6: nt everywhere + DIRECT stores (no LDS, no barrier). Each thread owns one
//     float4 of x/q and two full 64B lines of Q.

typedef float f4 __attribute__((ext_vector_type(4)));

constexpr int NB     = 8;
constexpr int TOTAL  = 8192 * 1024;        // LENGTH * PACKET
constexpr int NVEC   = TOTAL / 4;          // 2,097,152 float4 groups
constexpr int Q_OFF  = TOTAL;              // start of Q region (elements)
constexpr int W_OFF  = TOTAL * (NB + 1);   // start of W region (elements)
constexpr float VRC  = 1.0f / 256.0f;      // VR (exact power of two)
constexpr int NBLOCKS = NVEC / 256;        // 8192 blocks, 1 float4 per thread

__global__ __launch_bounds__(256) void sar_adc_kernel(
    const float* __restrict__ x,
    const float* __restrict__ W,
    float* __restrict__ out)
{
    // W uniform; constant indices -> s_loads/SGPRs.
    float w[36];
#pragma unroll
    for (int i = 0; i < 36; ++i) w[i] = W[i];

    if (blockIdx.x == 0 && threadIdx.x < 36) {
        out[W_OFF + threadIdx.x] = w[threadIdx.x];
    }

    const f4* __restrict__ x4 = (const f4*)x;
    f4* __restrict__ q4 = (f4*)out;
    f4* __restrict__ Q4 = (f4*)(out + Q_OFF);

    const int v = blockIdx.x * 256 + threadIdx.x;   // float4 index into x / q

    const f4 xv = __builtin_nontemporal_load(&x4[v]);  // read-once
    const float xe[4] = {xv.x, xv.y, xv.z, xv.w};
    float qout[4];
    float Qb[4][NB];

#pragma unroll
    for (int e = 0; e < 4; ++e) {
        // Work in the x/VR domain: all VR scalings are exact powers of two,
        // so sign decisions are bit-identical to the reference.
        const float xs = xe[e] * 256.0f;
        bool bit[NB];
        int m = 35;
#pragma unroll
        for (int j = NB - 1; j >= 0; --j) {
            float bs = w[m]; m--;            // W[m] * VREF (scaled out)
#pragma unroll
            for (int k = j + 1; k < NB; ++k) {
                // (Qk+1)/2 in {0,1}: select + add, reference accumulation order,
                // no multiply -> no FMA contraction rounding hazard.
                bs += bit[k] ? w[m] : 0.0f;
                m--;
            }
            // sign(diff + 1e-30): diff==0 -> +1; else sign(diff).
            bit[j] = (xs - bs) >= 0.0f;
        }
        int n = 0;
#pragma unroll
        for (int b = 0; b < NB; ++b) {
            Qb[e][b] = bit[b] ? 1.0f : -1.0f;
            n += bit[b] ? (1 << b) : 0;
        }
        qout[e] = (float)n * VRC;            // exact: n <= 255
    }

    {
        f4 qv = {qout[0], qout[1], qout[2], qout[3]};
        __builtin_nontemporal_store(qv, &q4[v]);   // coalesced, streaming
    }

    // Direct Q stores: thread owns float4 slots v*8 .. v*8+7 = two full,
    // consecutive 64B lines (L2 write-combines; no LDS roundtrip needed).
#pragma unroll
    for (int i = 0; i < 8; ++i) {
        const int e  = i >> 1;
        const int b0 = (i & 1) * 4;
        f4 qb = {Qb[e][b0 + 0], Qb[e][b0 + 1], Qb[e][b0 + 2], Qb[e][b0 + 3]};
        __builtin_nontemporal_store(qb, &Q4[(size_t)v * 8 + i]);
    }
}

extern "C" void kernel_launch(void* const* d_in, const int* in_sizes, int n_in,
                              void* d_out, int out_size, void* d_ws, size_t ws_size,
                              hipStream_t stream) {
    const float* x = (const float*)d_in[0];
    const float* W = (const float*)d_in[1];
    float* out = (float*)d_out;

    sar_adc_kernel<<<NBLOCKS, 256, 0, stream>>>(x, W, out);
}

// Round 7
// 167.110 us; speedup vs baseline: 2.9238x; 2.9238x over previous
//
#include <hip/hip_runtime.h>
#include <stdint.h>

// Bit-serial SAR ADC quantizer.
// Outputs concatenated in d_out: q [8192*1024] f32, Q [8192*1024*8] f32 (bit innermost), W [36] f32.
//
// R1: LDS-coalesced Q stores, regular: 167.8 us (vs R0 direct 158.7).
// R4: LDS-coalesced + nt builtins: 155.2 us (best fused).
// R5: asm sc0/sc1/nt write-around: FAILED (stale lines at read-back). Never bypass.
// R6: direct scattered + nt: 488 us, WRITE 4.3x, FETCH +80 MiB -> nt lines can't
//     merge partial writes in L2; each 16B store RMWs + early-evicts its line.
//     LAW: nt only when each store INSTRUCTION covers whole 64B lines.
// R7: producer/consumer split. A: x -> q + 1-byte sign codes (d_ws). B: pure
//     fill-like expander codes -> Q, fully coalesced nt dwordx4 (1024B/instr).
//     Harness fill kernel proves pure writers hit 6.9 TB/s vs our fused 2.2.

typedef float f4 __attribute__((ext_vector_type(4)));

constexpr int NB     = 8;
constexpr int TOTAL  = 8192 * 1024;        // LENGTH * PACKET
constexpr int NVEC   = TOTAL / 4;          // float4 / code-dword groups
constexpr int Q_OFF  = TOTAL;              // start of Q region (elements)
constexpr int W_OFF  = TOTAL * (NB + 1);   // start of W region (elements)
constexpr float VRC  = 1.0f / 256.0f;      // VR (exact power of two)
constexpr int NBLOCKS = NVEC / 256;        // 8192

// ---------------- Kernel A: compute q + packed sign codes ----------------
__global__ __launch_bounds__(256) void quant_code_kernel(
    const float* __restrict__ x,
    const float* __restrict__ W,
    float* __restrict__ out,
    uint32_t* __restrict__ codes4)
{
    float w[36];
#pragma unroll
    for (int i = 0; i < 36; ++i) w[i] = W[i];

    if (blockIdx.x == 0 && threadIdx.x < 36) {
        out[W_OFF + threadIdx.x] = w[threadIdx.x];
    }

    const f4* __restrict__ x4 = (const f4*)x;
    f4* __restrict__ q4 = (f4*)out;

    const int v = blockIdx.x * 256 + threadIdx.x;

    const f4 xv = __builtin_nontemporal_load(&x4[v]);
    const float xe[4] = {xv.x, xv.y, xv.z, xv.w};
    float qout[4];
    uint32_t code = 0;

#pragma unroll
    for (int e = 0; e < 4; ++e) {
        // x/VR domain: all VR scalings are exact powers of two, so sign
        // decisions are bit-identical to the reference.
        const float xs = xe[e] * 256.0f;
        bool bit[NB];
        int m = 35;
#pragma unroll
        for (int j = NB - 1; j >= 0; --j) {
            float bs = w[m]; m--;            // W[m] * VREF (scaled out)
#pragma unroll
            for (int k = j + 1; k < NB; ++k) {
                // select + add, reference accumulation order, no FMA hazard.
                bs += bit[k] ? w[m] : 0.0f;
                m--;
            }
            // sign(diff + 1e-30): diff==0 -> +1; else sign(diff).
            bit[j] = (xs - bs) >= 0.0f;
        }
        int n = 0;
#pragma unroll
        for (int b = 0; b < NB; ++b) n += bit[b] ? (1 << b) : 0;
        qout[e] = (float)n * VRC;            // exact: n <= 255
        code |= (uint32_t)n << (8 * e);      // byte e = element 4v+e
    }

    {
        f4 qv = {qout[0], qout[1], qout[2], qout[3]};
        __builtin_nontemporal_store(qv, &q4[v]);      // 1024B/wave, full lines
    }
    __builtin_nontemporal_store(code, &codes4[v]);    // 256B/wave, full lines
}

// ---------------- Kernel B: fill-like expander codes -> Q ----------------
__global__ __launch_bounds__(256) void expand_kernel(
    const uint8_t* __restrict__ codes,
    float* __restrict__ out)
{
    f4* __restrict__ Q4 = (f4*)(out + Q_OFF);
    const int tile = blockIdx.x;             // 1024 elements per block
    const int t    = threadIdx.x;
    const int ebase = tile * 1024;
    const size_t qbase = (size_t)tile * 2048;

#pragma unroll
    for (int s = 0; s < 8; ++s) {
        const int f = s * 256 + t;           // Q4 slot within tile
        // wave reads 32 consecutive code bytes -> one L1 line, broadcast-ish
        const uint32_t c = codes[ebase + (f >> 1)];
        const int b0 = (f & 1) * 4;
        f4 qb = { (c >> (b0 + 0)) & 1 ? 1.0f : -1.0f,
                  (c >> (b0 + 1)) & 1 ? 1.0f : -1.0f,
                  (c >> (b0 + 2)) & 1 ? 1.0f : -1.0f,
                  (c >> (b0 + 3)) & 1 ? 1.0f : -1.0f };
        // fully coalesced: 64 lanes x 16B contiguous = 1024B, full lines -> nt safe
        __builtin_nontemporal_store(qb, &Q4[qbase + f]);
    }
}

// ---------------- Fallback fused kernel (R4 path) if ws too small --------
__global__ __launch_bounds__(256) void sar_adc_fused(
    const float* __restrict__ x,
    const float* __restrict__ W,
    float* __restrict__ out)
{
    __shared__ f4 lds[2048];
    float w[36];
#pragma unroll
    for (int i = 0; i < 36; ++i) w[i] = W[i];
    if (blockIdx.x == 0 && threadIdx.x < 36) out[W_OFF + threadIdx.x] = w[threadIdx.x];

    const f4* __restrict__ x4 = (const f4*)x;
    f4* __restrict__ q4 = (f4*)out;
    f4* __restrict__ Q4 = (f4*)(out + Q_OFF);
    const int t = threadIdx.x, tile = blockIdx.x;
    const int vin = tile * 256 + t;

    const f4 xv = __builtin_nontemporal_load(&x4[vin]);
    const float xe[4] = {xv.x, xv.y, xv.z, xv.w};
    float qout[4]; float Qb[4][NB];
#pragma unroll
    for (int e = 0; e < 4; ++e) {
        const float xs = xe[e] * 256.0f;
        bool bit[NB]; int m = 35;
#pragma unroll
        for (int j = NB - 1; j >= 0; --j) {
            float bs = w[m]; m--;
#pragma unroll
            for (int k = j + 1; k < NB; ++k) { bs += bit[k] ? w[m] : 0.0f; m--; }
            bit[j] = (xs - bs) >= 0.0f;
        }
        int n = 0;
#pragma unroll
        for (int b = 0; b < NB; ++b) { Qb[e][b] = bit[b] ? 1.0f : -1.0f; n += bit[b] ? (1 << b) : 0; }
        qout[e] = (float)n * VRC;
    }
    { f4 qv = {qout[0], qout[1], qout[2], qout[3]}; __builtin_nontemporal_store(qv, &q4[vin]); }
#pragma unroll
    for (int i = 0; i < 8; ++i) {
        const int e = i >> 1, b0 = (i & 1) * 4;
        f4 qb = {Qb[e][b0+0], Qb[e][b0+1], Qb[e][b0+2], Qb[e][b0+3]};
        lds[t * 8 + (i ^ (t & 7))] = qb;
    }
    __syncthreads();
    const int qbase = tile * 2048;
#pragma unroll
    for (int s = 0; s < 8; ++s) {
        const int f = s * 256 + t, tw = f >> 3, iw = f & 7;
        __builtin_nontemporal_store(lds[tw * 8 + (iw ^ (tw & 7))], &Q4[qbase + f]);
    }
}

extern "C" void kernel_launch(void* const* d_in, const int* in_sizes, int n_in,
                              void* d_out, int out_size, void* d_ws, size_t ws_size,
                              hipStream_t stream) {
    const float* x = (const float*)d_in[0];
    const float* W = (const float*)d_in[1];
    float* out = (float*)d_out;

    if (ws_size >= (size_t)TOTAL) {   // need 8.4 MB for codes
        uint32_t* codes4 = (uint32_t*)d_ws;
        quant_code_kernel<<<NBLOCKS, 256, 0, stream>>>(x, W, out, codes4);
        expand_kernel<<<NBLOCKS, 256, 0, stream>>>((const uint8_t*)d_ws, out);
    } else {
        sar_adc_fused<<<NBLOCKS, 256, 0, stream>>>(x, W, out);
    }
}

// Round 9
// 166.004 us; speedup vs baseline: 2.9433x; 1.0067x over previous
//
#include <hip/hip_runtime.h>
#include <stdint.h>

// Bit-serial SAR ADC quantizer.
// Outputs concatenated in d_out: q [8192*1024] f32, Q [8192*1024*8] f32 (bit innermost), W [36] f32.
//
// Ladder: R0 direct plain 158.7 / R1 LDS plain 167.8 / R4 LDS+nt 155.2 /
//   R6 scattered+nt 488 (nt partial-line RMW disaster) / R7 split+nt 167.1.
// R5/R8 LAW: sc0sc1 write-around stores are UNRECOVERABLE here — the harness
//   memset leaves stale zero lines in the MALL (Infinity Cache), which kernel
//   code cannot invalidate (buffer_wbl2/inv is L2-only). Evidence: q (MALL-
//   evicted region) validated OK, Q (MALL-resident region) read stale zeros.
//   All stores must use the normal allocate path.
// R9: split producer/consumer with ALL nt hints removed. Theory: nt evict-
//   first defeats L2 write-merging/MALL absorption for the pure streaming
//   expander (the harness fill kernel = plain stores = 6.9 TB/s), and nt on
//   code loads keeps the 8.4 MB code array out of cache. Split+plain is the
//   last untested cell of the {fused,split} x {plain,nt} matrix.

typedef float f4 __attribute__((ext_vector_type(4)));

constexpr int NB     = 8;
constexpr int TOTAL  = 8192 * 1024;        // LENGTH * PACKET
constexpr int NVEC   = TOTAL / 4;          // float4 / code-dword groups
constexpr int Q_OFF  = TOTAL;              // start of Q region (elements)
constexpr int W_OFF  = TOTAL * (NB + 1);   // start of W region (elements)
constexpr float VRC  = 1.0f / 256.0f;      // VR (exact power of two)
constexpr int NBLOCKS = NVEC / 256;        // 8192

// ---------------- Kernel A: compute q + packed sign codes ----------------
__global__ __launch_bounds__(256) void quant_code_kernel(
    const float* __restrict__ x,
    const float* __restrict__ W,
    float* __restrict__ out,
    uint32_t* __restrict__ codes4)
{
    float w[36];
#pragma unroll
    for (int i = 0; i < 36; ++i) w[i] = W[i];

    if (blockIdx.x == 0 && threadIdx.x < 36) {
        out[W_OFF + threadIdx.x] = w[threadIdx.x];
    }

    const f4* __restrict__ x4 = (const f4*)x;
    f4* __restrict__ q4 = (f4*)out;

    const int v = blockIdx.x * 256 + threadIdx.x;

    const f4 xv = x4[v];                      // plain, coalesced
    const float xe[4] = {xv.x, xv.y, xv.z, xv.w};
    float qout[4];
    uint32_t code = 0;

#pragma unroll
    for (int e = 0; e < 4; ++e) {
        // x/VR domain: all VR scalings are exact powers of two, so sign
        // decisions are bit-identical to the reference.
        const float xs = xe[e] * 256.0f;
        bool bit[NB];
        int m = 35;
#pragma unroll
        for (int j = NB - 1; j >= 0; --j) {
            float bs = w[m]; m--;            // W[m] * VREF (scaled out)
#pragma unroll
            for (int k = j + 1; k < NB; ++k) {
                // select + add, reference accumulation order, no FMA hazard.
                bs += bit[k] ? w[m] : 0.0f;
                m--;
            }
            // sign(diff + 1e-30): diff==0 -> +1; else sign(diff).
            bit[j] = (xs - bs) >= 0.0f;
        }
        int n = 0;
#pragma unroll
        for (int b = 0; b < NB; ++b) n += bit[b] ? (1 << b) : 0;
        qout[e] = (float)n * VRC;            // exact: n <= 255
        code |= (uint32_t)n << (8 * e);      // byte e = element 4v+e
    }

    {
        f4 qv = {qout[0], qout[1], qout[2], qout[3]};
        q4[v] = qv;                          // plain, 1024B/wave
    }
    codes4[v] = code;                        // plain, 256B/wave
}

// ---------------- Kernel B: fill-like expander codes -> Q ----------------
__global__ __launch_bounds__(256) void expand_kernel(
    const uint8_t* __restrict__ codes,
    float* __restrict__ out)
{
    f4* __restrict__ Q4 = (f4*)(out + Q_OFF);
    const int tile = blockIdx.x;             // 1024 elements per block
    const int t    = threadIdx.x;
    const int ebase = tile * 1024;
    const size_t qbase = (size_t)tile * 2048;

#pragma unroll
    for (int s = 0; s < 8; ++s) {
        const int f = s * 256 + t;           // Q4 slot within tile
        // wave reads 32 consecutive code bytes -> one cache line (L1/L2-hot)
        const uint32_t c = codes[ebase + (f >> 1)];
        const int b0 = (f & 1) * 4;
        f4 qb = { (c >> (b0 + 0)) & 1 ? 1.0f : -1.0f,
                  (c >> (b0 + 1)) & 1 ? 1.0f : -1.0f,
                  (c >> (b0 + 2)) & 1 ? 1.0f : -1.0f,
                  (c >> (b0 + 3)) & 1 ? 1.0f : -1.0f };
        // fully coalesced plain store: 64 lanes x 16B contiguous = 1024B
        Q4[qbase + f] = qb;
    }
}

extern "C" void kernel_launch(void* const* d_in, const int* in_sizes, int n_in,
                              void* d_out, int out_size, void* d_ws, size_t ws_size,
                              hipStream_t stream) {
    const float* x = (const float*)d_in[0];
    const float* W = (const float*)d_in[1];
    float* out = (float*)d_out;

    uint32_t* codes4 = (uint32_t*)d_ws;      // 8.4 MB of the workspace
    quant_code_kernel<<<NBLOCKS, 256, 0, stream>>>(x, W, out, codes4);
    expand_kernel<<<NBLOCKS, 256, 0, stream>>>((const uint8_t*)d_ws, out);
}